// Round 19
// baseline (166.647 us; speedup 1.0000x reference)
//
#include <hip/hip_runtime.h>

// get_fc_pix_discriminator_1x1_solo: fused 5-layer per-pixel MLP + BCE mean.
// B=4, C=19, H=256, W=512 -> 524288 px. dims 19->64->128->256->512->1.
// R19 = R18 (fp8, 21-phase tri-buffered counted-vmcnt pipeline, 5 waves/SIMD)
// with L4 moved to MX-scaled mfma_scale_f32_16x16x128_f8f6f4 (scales = 1.0,
// E8M0 0x7F -> math identical to non-scaled fp8). Rationale: R18 counters
// show VALUBusy 54% + MfmaUtil 44.5% ~= 98.5% -- SIMD issue/execute saturated
// by instruction count; occupancy ladder stalled. K=128 cuts L4's MFMA count
// 512 -> 128 insts/wave at ~2x FLOP rate (m148 ladder step).
// W4 prepass layout: frag[ob][q] = 2048B; two 16B halves per lane in separate
// 1KB regions -> both ds_read_b128 conflict-free. sigma' chosen so the B
// operand is the plain register concat of h3[pb][4q..4q+3] (hoisted once).

#define HW_ 131072      // 256*512 = 2^17
#define NPIX 524288

using bf16x8 = __attribute__((ext_vector_type(8))) short;
using f32x4  = __attribute__((ext_vector_type(4))) float;
using f32x2  = __attribute__((ext_vector_type(2))) float;
using fp8x8  = long;    // 8 fp8 bytes in one 64b register pair
using i32x4t = __attribute__((ext_vector_type(4))) int;
using i32x8t = __attribute__((ext_vector_type(8))) int;

#define MFMA  __builtin_amdgcn_mfma_f32_16x16x32_bf16
#define MFMA8 __builtin_amdgcn_mfma_f32_16x16x32_fp8_fp8
#define VMCNT2 asm volatile("s_waitcnt vmcnt(2)" ::: "memory")
#define VMCNT0 asm volatile("s_waitcnt vmcnt(0)" ::: "memory")
#define BAR __builtin_amdgcn_s_barrier()
#define SCHED0 __builtin_amdgcn_sched_barrier(0)

__device__ __forceinline__ unsigned short f2bf(float f) {
  unsigned u = __builtin_bit_cast(unsigned, f);
  u += 0x7FFFu + ((u >> 16) & 1u);   // round-to-nearest-even
  return (unsigned short)(u >> 16);
}

// sigma^-1: k-slot -> source feature index (within 32-chunks)
__device__ __forceinline__ int kinv(int k) {
  return ((k >> 5) << 5) + (((k >> 2) & 1) << 4) + (((k >> 3) & 3) << 2) + (k & 3);
}

// f32 -> fp8 e4m3 byte (RNE, saturating) via the HW packed converter
__device__ __forceinline__ unsigned char f2fp8(float f) {
  int v = __builtin_amdgcn_cvt_pk_fp8_f32(f, 0.f, 0, false);
  return (unsigned char)(v & 0xFF);
}

// ---- weight fp8 pre-conversion ---------------------------------------------
// W1/W2/W3: 16x16x32 A-frag order: [ob][ks][lane][j 0..8); 512B frags;
//   o = ob*16+(lane&15), k = ks*32+(lane>>4)*8+j, f = PERM ? kinv(k) : k.
// W4 (scaled K=128): frag[ob][q] = 2048B; byte = h*1024 + lane*16 + (j&15),
//   h=j>>4; o = ob*16+(lane&15);
//   f = 128q + 32*(j>>3) + 16*((j>>2)&1) + 4*(lane>>4) + (j&3).
#define OW1 0
#define OW2 2048
#define OW3 10240
#define OW4 43008
#define WTOT 174080

template <int K0, int KP, bool PERM>
__device__ __forceinline__ void conv_layer(const float* __restrict__ W,
                                           unsigned char* __restrict__ out,
                                           int i) {
  int r9 = i & 511;
  int lane = r9 >> 3, j = r9 & 7;
  int frag = i >> 9;               // = ob*KS + ks
  constexpr int KS = KP / 32;
  int ob = frag / KS, ks = frag - ob * KS;
  int o = ob * 16 + (lane & 15);
  int k = ks * 32 + ((lane >> 4) << 3) + j;
  int f = PERM ? kinv(k) : k;
  out[i] = f2fp8(f < K0 ? W[o * K0 + f] : 0.f);
}

__global__ void wconv_kernel(const float* __restrict__ W1, const float* __restrict__ W2,
                             const float* __restrict__ W3, const float* __restrict__ W4,
                             unsigned char* __restrict__ wb) {
  int i = blockIdx.x * 256 + threadIdx.x;
  if (i < OW2) {
    conv_layer<19, 32, false>(W1, wb + OW1, i - OW1);
  } else if (i < OW3) {
    conv_layer<64, 64, true>(W2, wb + OW2, i - OW2);
  } else if (i < OW4) {
    conv_layer<128, 128, true>(W3, wb + OW3, i - OW3);
  } else if (i < WTOT) {
    int ii = i - OW4;
    int frag = ii >> 11;           // ob*2 + q
    int within = ii & 2047;
    int h = within >> 10;
    int rem = within & 1023;
    int lane = rem >> 4, jj = rem & 15;
    int j = h * 16 + jj;           // 0..31
    int ob = frag >> 1, q = frag & 1;
    int f = 128 * q + 32 * (j >> 3) + 16 * ((j >> 2) & 1) +
            ((lane >> 4) << 2) + (j & 3);
    int o = ob * 16 + (lane & 15);
    wb[i] = f2fp8(W4[o * 256 + f]);
  }
}

// ---- packed-f32 helpers (VOP3P) -------------------------------------------
__device__ __forceinline__ f32x2 pk_mul(f32x2 a, f32x2 b) {
  f32x2 d;
  asm("v_pk_mul_f32 %0, %1, %2" : "=v"(d) : "v"(a), "v"(b));
  return d;
}
__device__ __forceinline__ f32x2 pk_fma(f32x2 a, f32x2 b, f32x2 c) {
  f32x2 d;
  asm("v_pk_fma_f32 %0, %1, %2, %3" : "=v"(d) : "v"(a), "v"(b), "v"(c));
  return d;
}

__device__ __forceinline__ f32x4 leaky4(f32x4 v) {
  f32x2 c = {0.2f, 0.2f};
  f32x2 lo = {v[0], v[1]}, hi = {v[2], v[3]};
  f32x2 ml = pk_mul(lo, c), mh = pk_mul(hi, c);
  f32x4 r;
  r[0] = fmaxf(v[0], ml[0]);
  r[1] = fmaxf(v[1], ml[1]);
  r[2] = fmaxf(v[2], mh[0]);
  r[3] = fmaxf(v[3], mh[1]);
  return r;
}

// pack 8 f32 -> 8 fp8 bytes (j order: e[0..3] -> bytes 0-3, o[0..3] -> 4-7)
__device__ __forceinline__ fp8x8 pack8f8(f32x4 e, f32x4 o) {
  int lo = __builtin_amdgcn_cvt_pk_fp8_f32(e[0], e[1], 0, false);
  lo = __builtin_amdgcn_cvt_pk_fp8_f32(e[2], e[3], lo, true);
  int hi = __builtin_amdgcn_cvt_pk_fp8_f32(o[0], o[1], 0, false);
  hi = __builtin_amdgcn_cvt_pk_fp8_f32(o[2], o[3], hi, true);
  return (long)(((unsigned long)(unsigned)hi << 32) | (unsigned)lo);
}

// four 8-byte frags -> one 32-byte scaled-MFMA operand (register concat)
__device__ __forceinline__ i32x8t mkop(fp8x8 a0, fp8x8 a1, fp8x8 a2, fp8x8 a3) {
  union { long l; int i[2]; } u0{a0}, u1{a1}, u2{a2}, u3{a3};
  i32x8t r;
  r[0] = u0.i[0]; r[1] = u0.i[1]; r[2] = u1.i[0]; r[3] = u1.i[1];
  r[4] = u2.i[0]; r[5] = u2.i[1]; r[6] = u3.i[0]; r[7] = u3.i[1];
  return r;
}

// ---- async global -> LDS staging (16B/lane, identity layout) --------------
__device__ __forceinline__ void gl16(const unsigned char* g, unsigned char* l) {
  __builtin_amdgcn_global_load_lds(
      (const __attribute__((address_space(1))) unsigned int*)(const void*)g,
      (__attribute__((address_space(3))) unsigned int*)(void*)l, 16, 0, 0);
}
// one 8KB chunk = 8 x 1KB segments; 4 waves round-robin (2 segs/wave)
__device__ __forceinline__ void stage8(const unsigned char* __restrict__ g,
                                       unsigned char* l, int wave, int lane) {
#pragma unroll
  for (int i = 0; i < 2; i++) {
    int s = wave + 4 * i;
    gl16(g + (s << 10) + (lane << 4), l + (s << 10));
  }
}

// frag read from LDS chunk: local frag lf (512B each), lane-linear 8B
#define LDF8(bufp, lf) (*(const fp8x8*)((bufp) + ((lf) << 9) + (lane << 3)))

__global__ __launch_bounds__(256) __attribute__((amdgpu_waves_per_eu(5, 5)))
void disc_lds(const float* __restrict__ x, const float* __restrict__ lbl,
              const unsigned char* __restrict__ wb8,
              const float* __restrict__ b1, const float* __restrict__ b2,
              const float* __restrict__ b3, const float* __restrict__ b4,
              const float* __restrict__ W5f, const float* __restrict__ b5,
              float* __restrict__ out) {
  __shared__ __align__(16) unsigned char sb[24576];  // 3 x 8KB tri-buffer

  int t = threadIdx.x;
  int wave = t >> 6, lane = t & 63;
  int g = lane >> 4, li = lane & 15;
  long px0 = ((long)blockIdx.x * 4 + wave) * 32;   // 32 px per wave
  int b = (int)(px0 >> 17);
  int hw0 = (int)(px0 & (HW_ - 1));

  // ---- W1 frags direct global->reg (2KB, L2-resident broadcast) ----------
  fp8x8 fW1[4];
#pragma unroll
  for (int f = 0; f < 4; f++)
    fW1[f] = *(const fp8x8*)(wb8 + (f << 9) + (lane << 3));

  // ---- x -> fp8 B-frags (k = input channel c; c>=19 zero) -----------------
  fp8x8 xb[2];
#pragma unroll
  for (int pb = 0; pb < 2; pb++) {
    const float* xp = x + (((long)b * 19) << 17) + hw0 + pb * 16 + li;
    f32x4 e, o;
#pragma unroll
    for (int j = 0; j < 4; j++) {
      int c = 8 * g + j;
      e[j] = (c < 19) ? xp[(long)c << 17] : 0.f;
      int c2 = 8 * g + 4 + j;
      o[j] = (c2 < 19) ? xp[(long)c2 << 17] : 0.f;
    }
    xb[pb] = pack8f8(e, o);
  }

  // ---- issue pipeline chunks 0 (W2 -> buf0) and 1 (W3a -> buf1) -----------
  stage8(wb8 + OW2, sb, wave, lane);
  stage8(wb8 + OW3, sb + 8192, wave, lane);

  // ---- L1: 19->64 from fW1 regs -------------------------------------------
  fp8x8 h1[2][2];
#pragma unroll
  for (int obp = 0; obp < 2; obp++) {
    f32x4 bE = *(const f32x4*)(b1 + 32 * obp + 4 * g);
    f32x4 bO = *(const f32x4*)(b1 + 32 * obp + 16 + 4 * g);
    f32x4 aE[2], aO[2];
#pragma unroll
    for (int pb = 0; pb < 2; pb++) {
      aE[pb] = MFMA8(fW1[2 * obp], xb[pb], bE, 0, 0, 0);
      aO[pb] = MFMA8(fW1[2 * obp + 1], xb[pb], bO, 0, 0, 0);
    }
#pragma unroll
    for (int pb = 0; pb < 2; pb++)
      h1[pb][obp] = pack8f8(leaky4(aE[pb]), leaky4(aO[pb]));
  }

  // ---- phase 0: L2 from buf0 (chunk 0 = W2); stage chunk 2 -> buf2 --------
  VMCNT2; BAR; SCHED0;
  stage8(wb8 + OW3 + 8192, sb + 16384, wave, lane);
  fp8x8 h2[2][4];
  {
    const unsigned char* cur = sb;
#pragma unroll
    for (int obp = 0; obp < 4; obp++) {
      fp8x8 fE0 = LDF8(cur, 4 * obp);
      fp8x8 fE1 = LDF8(cur, 4 * obp + 1);
      fp8x8 fO0 = LDF8(cur, 4 * obp + 2);
      fp8x8 fO1 = LDF8(cur, 4 * obp + 3);
      f32x4 bE = *(const f32x4*)(b2 + 32 * obp + 4 * g);
      f32x4 bO = *(const f32x4*)(b2 + 32 * obp + 16 + 4 * g);
      f32x4 aE[2], aO[2];
#pragma unroll
      for (int pb = 0; pb < 2; pb++) {
        aE[pb] = MFMA8(fE0, h1[pb][0], bE, 0, 0, 0);
        aE[pb] = MFMA8(fE1, h1[pb][1], aE[pb], 0, 0, 0);
        aO[pb] = MFMA8(fO0, h1[pb][0], bO, 0, 0, 0);
        aO[pb] = MFMA8(fO1, h1[pb][1], aO[pb], 0, 0, 0);
      }
#pragma unroll
      for (int pb = 0; pb < 2; pb++)
        h2[pb][obp] = pack8f8(leaky4(aE[pb]), leaky4(aO[pb]));
    }
  }

  // ---- phases 1-4: L3 (chunk c=1+k covers obp {2k, 2k+1}) -----------------
  fp8x8 h3[2][8];
#pragma unroll
  for (int k = 0; k < 4; k++) {
    int c = 1 + k;
    VMCNT2; BAR; SCHED0;
    // stage chunk c+2: chunks 3,4 = W3 tail; 5,6 = W4 head
    int cc = c + 2;
    const unsigned char* src = (cc <= 4) ? (wb8 + OW3 + ((cc - 1) << 13))
                                         : (wb8 + OW4 + ((cc - 5) << 13));
    stage8(src, sb + ((cc % 3) << 13), wave, lane);
    const unsigned char* cur = sb + ((c % 3) << 13);
#pragma unroll
    for (int o = 0; o < 2; o++) {
      int obp = 2 * k + o;
      f32x4 bE = *(const f32x4*)(b3 + 32 * obp + 4 * g);
      f32x4 bO = *(const f32x4*)(b3 + 32 * obp + 16 + 4 * g);
      f32x4 aE[2], aO[2];
#pragma unroll
      for (int pb = 0; pb < 2; pb++) { aE[pb] = bE; aO[pb] = bO; }
#pragma unroll
      for (int ks = 0; ks < 4; ks++) {
        fp8x8 fE = LDF8(cur, o * 8 + ks);
        fp8x8 fO = LDF8(cur, o * 8 + 4 + ks);
#pragma unroll
        for (int pb = 0; pb < 2; pb++) {
          aE[pb] = MFMA8(fE, h2[pb][ks], aE[pb], 0, 0, 0);
          aO[pb] = MFMA8(fO, h2[pb][ks], aO[pb], 0, 0, 0);
        }
      }
#pragma unroll
      for (int pb = 0; pb < 2; pb++)
        h3[pb][obp] = pack8f8(leaky4(aE[pb]), leaky4(aO[pb]));
    }
  }

  // ---- hoist scaled-MFMA B operands: Bop[pb][q] = h3[pb][4q..4q+3] --------
  i32x8t Bop[2][2];
#pragma unroll
  for (int pb = 0; pb < 2; pb++)
#pragma unroll
    for (int q = 0; q < 2; q++)
      Bop[pb][q] = mkop(h3[pb][4 * q], h3[pb][4 * q + 1],
                        h3[pb][4 * q + 2], h3[pb][4 * q + 3]);

  // ---- phases 5-20: L4+L5 via mfma_scale 16x16x128 (2 insts/ob/pb) --------
  f32x2 zplo[2], zphi[2];
#pragma unroll
  for (int pb = 0; pb < 2; pb++) {
    zplo[pb] = f32x2{0.f, 0.f};
    zphi[pb] = f32x2{0.f, 0.f};
  }

#pragma unroll 1
  for (int c = 5; c <= 20; c++) {
    if (c == 20) { VMCNT0; } else { VMCNT2; }
    BAR; SCHED0;
    if (c + 2 <= 20)
      stage8(wb8 + OW4 + ((c - 3) << 13), sb + (((c + 2) % 3) << 13),
             wave, lane);
    const unsigned char* cur = sb + ((c % 3) << 13);
    int ob0 = 2 * (c - 5);
#pragma unroll
    for (int oo = 0; oo < 2; oo++) {
      int ob = ob0 + oo;
      f32x4 bv = *(const f32x4*)(b4 + 16 * ob + 4 * g);
      f32x4 w5v = *(const f32x4*)(W5f + 16 * ob + 4 * g);
      f32x4 a[2];
#pragma unroll
      for (int pb = 0; pb < 2; pb++) a[pb] = bv;
#pragma unroll
      for (int q = 0; q < 2; q++) {
        const unsigned char* fragp = cur + (((oo << 1) | q) << 11);
        i32x4t alo = *(const i32x4t*)(fragp + (lane << 4));
        i32x4t ahi = *(const i32x4t*)(fragp + 1024 + (lane << 4));
        i32x8t A;
        A[0] = alo[0]; A[1] = alo[1]; A[2] = alo[2]; A[3] = alo[3];
        A[4] = ahi[0]; A[5] = ahi[1]; A[6] = ahi[2]; A[7] = ahi[3];
#pragma unroll
        for (int pb = 0; pb < 2; pb++)
          a[pb] = __builtin_amdgcn_mfma_scale_f32_16x16x128_f8f6f4(
              A, Bop[pb][q], a[pb], 0, 0, 0, 0x7F7F7F7F, 0, 0x7F7F7F7F);
      }
#pragma unroll
      for (int pb = 0; pb < 2; pb++) {
        f32x4 lv = leaky4(a[pb]);
        zplo[pb] = pk_fma(f32x2{lv[0], lv[1]}, f32x2{w5v[0], w5v[1]}, zplo[pb]);
        zphi[pb] = pk_fma(f32x2{lv[2], lv[3]}, f32x2{w5v[2], w5v[3]}, zphi[pb]);
      }
    }
  }

  // ---- z per pixel + BCE + reduction (reuse sb bytes for 4 floats) --------
  float zb[2];
#pragma unroll
  for (int pb = 0; pb < 2; pb++) {
    float s = zplo[pb][0] + zplo[pb][1] + zphi[pb][0] + zphi[pb][1];
    s += __shfl_xor(s, 16);
    s += __shfl_xor(s, 32);
    zb[pb] = s;  // full z for px (pb,li), replicated across g
  }
  // lanes 0-15 -> pb0 px, lanes 16-31 -> pb1 px, lanes 32-63 idle
  float w = 0.f;
  if (lane < 32) {
    float z = ((lane & 16) ? zb[1] : zb[0]) + b5[0];
    float lab = lbl[px0 + lane];
    w = fmaxf(z, 0.f) - z * lab + log1pf(expf(-fabsf(z)));
  }
#pragma unroll
  for (int m = 1; m <= 32; m <<= 1) w += __shfl_xor(w, m);
  float* zsp = (float*)sb;   // chunk-20 region is sb+16384; sb+0 is free
  if (lane == 0) zsp[wave] = w;
  __syncthreads();
  if (t == 0)
    atomicAdd(out, (zsp[0] + zsp[1] + zsp[2] + zsp[3]) * (1.f / (float)NPIX));
}

// ---- fallback (ws too small): bf16 register-chained kernel, direct gather -
__device__ __forceinline__ f32x4 leaky4s(f32x4 v) {
  f32x4 r;
#pragma unroll
  for (int i = 0; i < 4; i++) r[i] = fmaxf(v[i], 0.2f * v[i]);
  return r;
}
__device__ __forceinline__ unsigned cvtpk(float lo, float hi) {
  unsigned r;
  asm("v_cvt_pk_bf16_f32 %0, %1, %2" : "=v"(r) : "v"(lo), "v"(hi));
  return r;
}
__device__ __forceinline__ bf16x8 pack8(f32x4 e, f32x4 o) {
  union { unsigned u[4]; bf16x8 v; } r;
  r.u[0] = cvtpk(e[0], e[1]);
  r.u[1] = cvtpk(e[2], e[3]);
  r.u[2] = cvtpk(o[0], o[1]);
  r.u[3] = cvtpk(o[2], o[3]);
  return r.v;
}
#define LDAG(dst, Wf, K0, KP, PERM, ob, ks)                                    \
  do {                                                                         \
    int o_ = (ob) * 16 + li;                                                   \
    for (int j_ = 0; j_ < 8; j_++) {                                           \
      int k_ = (ks) * 32 + (g << 3) + j_;                                      \
      int f_ = (PERM) ? kinv(k_) : k_;                                         \
      float v_ = f_ < (K0) ? (Wf)[o_ * (K0) + f_] : 0.f;                       \
      dst[j_] = (short)f2bf(v_);                                               \
    }                                                                          \
  } while (0)

__global__ __launch_bounds__(256, 1) void disc_fb(
    const float* __restrict__ x, const float* __restrict__ lbl,
    const float* __restrict__ W1f, const float* __restrict__ b1,
    const float* __restrict__ W2f, const float* __restrict__ b2,
    const float* __restrict__ W3f, const float* __restrict__ b3,
    const float* __restrict__ W4f, const float* __restrict__ b4,
    const float* __restrict__ W5f, const float* __restrict__ b5,
    float* __restrict__ out) {
  __shared__ float zs[4];
  int t = threadIdx.x;
  int wave = t >> 6, lane = t & 63;
  int g = lane >> 4, li = lane & 15;
  long px0 = ((long)blockIdx.x * 4 + wave) * 64;
  int b = (int)(px0 >> 17);
  int hw0 = (int)(px0 & (HW_ - 1));

  bf16x8 xb[4];
#pragma unroll
  for (int pb = 0; pb < 4; pb++) {
    const float* xp = x + (((long)b * 19) << 17) + hw0 + pb * 16 + li;
    bf16x8 v;
#pragma unroll
    for (int j = 0; j < 8; j++) {
      int c = 8 * g + j;
      float f = (c < 19) ? xp[(long)c << 17] : 0.f;
      v[j] = (short)f2bf(f);
    }
    xb[pb] = v;
  }

  bf16x8 h1[4][2];
#pragma unroll
  for (int obp = 0; obp < 2; obp++) {
    bf16x8 fE, fO;
    LDAG(fE, W1f, 19, 32, false, 2 * obp, 0);
    LDAG(fO, W1f, 19, 32, false, 2 * obp + 1, 0);
    f32x4 bE = *(const f32x4*)(b1 + 32 * obp + 4 * g);
    f32x4 bO = *(const f32x4*)(b1 + 32 * obp + 16 + 4 * g);
#pragma unroll
    for (int pb = 0; pb < 4; pb++) {
      f32x4 aE = MFMA(fE, xb[pb], bE, 0, 0, 0);
      f32x4 aO = MFMA(fO, xb[pb], bO, 0, 0, 0);
      h1[pb][obp] = pack8(leaky4s(aE), leaky4s(aO));
    }
  }

  bf16x8 h2[4][4];
#pragma unroll
  for (int obp = 0; obp < 4; obp++) {
    bf16x8 fE0, fE1, fO0, fO1;
    LDAG(fE0, W2f, 64, 64, true, 2 * obp, 0);
    LDAG(fE1, W2f, 64, 64, true, 2 * obp, 1);
    LDAG(fO0, W2f, 64, 64, true, 2 * obp + 1, 0);
    LDAG(fO1, W2f, 64, 64, true, 2 * obp + 1, 1);
    f32x4 bE = *(const f32x4*)(b2 + 32 * obp + 4 * g);
    f32x4 bO = *(const f32x4*)(b2 + 32 * obp + 16 + 4 * g);
#pragma unroll
    for (int pb = 0; pb < 4; pb++) {
      f32x4 aE = MFMA(fE0, h1[pb][0], bE, 0, 0, 0);
      aE = MFMA(fE1, h1[pb][1], aE, 0, 0, 0);
      f32x4 aO = MFMA(fO0, h1[pb][0], bO, 0, 0, 0);
      aO = MFMA(fO1, h1[pb][1], aO, 0, 0, 0);
      h2[pb][obp] = pack8(leaky4s(aE), leaky4s(aO));
    }
  }

  bf16x8 h3[4][8];
#pragma unroll
  for (int obp = 0; obp < 8; obp++) {
    f32x4 bE = *(const f32x4*)(b3 + 32 * obp + 4 * g);
    f32x4 bO = *(const f32x4*)(b3 + 32 * obp + 16 + 4 * g);
    f32x4 aE[4], aO[4];
#pragma unroll
    for (int pb = 0; pb < 4; pb++) { aE[pb] = bE; aO[pb] = bO; }
#pragma unroll
    for (int ks = 0; ks < 4; ks++) {
      bf16x8 fE, fO;
      LDAG(fE, W3f, 128, 128, true, 2 * obp, ks);
      LDAG(fO, W3f, 128, 128, true, 2 * obp + 1, ks);
#pragma unroll
      for (int pb = 0; pb < 4; pb++) {
        aE[pb] = MFMA(fE, h2[pb][ks], aE[pb], 0, 0, 0);
        aO[pb] = MFMA(fO, h2[pb][ks], aO[pb], 0, 0, 0);
      }
    }
#pragma unroll
    for (int pb = 0; pb < 4; pb++)
      h3[pb][obp] = pack8(leaky4s(aE[pb]), leaky4s(aO[pb]));
  }

  f32x4 zp[4];
#pragma unroll
  for (int pb = 0; pb < 4; pb++) zp[pb] = f32x4{0.f, 0.f, 0.f, 0.f};

  for (int ob = 0; ob < 32; ob++) {
    f32x4 bv = *(const f32x4*)(b4 + 16 * ob + 4 * g);
    f32x4 w5v = *(const f32x4*)(W5f + 16 * ob + 4 * g);
    f32x4 a[4];
#pragma unroll
    for (int pb = 0; pb < 4; pb++) a[pb] = bv;
#pragma unroll
    for (int ks = 0; ks < 8; ks++) {
      bf16x8 f4;
      LDAG(f4, W4f, 256, 256, true, ob, ks);
#pragma unroll
      for (int pb = 0; pb < 4; pb++) a[pb] = MFMA(f4, h3[pb][ks], a[pb], 0, 0, 0);
    }
#pragma unroll
    for (int pb = 0; pb < 4; pb++) {
      f32x4 lv = leaky4s(a[pb]);
#pragma unroll
      for (int i = 0; i < 4; i++) zp[pb][i] = fmaf(lv[i], w5v[i], zp[pb][i]);
    }
  }

  float zb[4];
#pragma unroll
  for (int pb = 0; pb < 4; pb++) {
    float s = zp[pb][0] + zp[pb][1] + zp[pb][2] + zp[pb][3];
    s += __shfl_xor(s, 16);
    s += __shfl_xor(s, 32);
    zb[pb] = s;
  }
  float zsel = (g == 0) ? zb[0] : (g == 1) ? zb[1] : (g == 2) ? zb[2] : zb[3];
  float z = zsel + b5[0];
  float lab = lbl[px0 + lane];
  float w = fmaxf(z, 0.f) - z * lab + log1pf(expf(-fabsf(z)));
#pragma unroll
  for (int m = 1; m <= 32; m <<= 1) w += __shfl_xor(w, m);
  if (lane == 0) zs[wave] = w;
  __syncthreads();
  if (t == 0)
    atomicAdd(out, (zs[0] + zs[1] + zs[2] + zs[3]) * (1.f / (float)NPIX));
}

extern "C" void kernel_launch(void* const* d_in, const int* in_sizes, int n_in,
                              void* d_out, int out_size, void* d_ws, size_t ws_size,
                              hipStream_t stream) {
  const float* x   = (const float*)d_in[0];
  const float* lbl = (const float*)d_in[1];
  const float* W1  = (const float*)d_in[2];
  const float* b1  = (const float*)d_in[3];
  const float* W2  = (const float*)d_in[4];
  const float* b2  = (const float*)d_in[5];
  const float* W3  = (const float*)d_in[6];
  const float* b3  = (const float*)d_in[7];
  const float* W4  = (const float*)d_in[8];
  const float* b4  = (const float*)d_in[9];
  const float* W5  = (const float*)d_in[10];
  const float* b5  = (const float*)d_in[11];
  float* out = (float*)d_out;

  (void)hipMemsetAsync(d_out, 0, sizeof(float), stream);

  bool pre = ws_size >= (size_t)WTOT;
  if (pre) {
    unsigned char* wbp = (unsigned char*)d_ws;
    wconv_kernel<<<(WTOT + 255) / 256, 256, 0, stream>>>(W1, W2, W3, W4, wbp);
    disc_lds<<<NPIX / 128, 256, 0, stream>>>(x, lbl, wbp, b1, b2, b3, b4, W5, b5, out);
  } else {
    disc_fb<<<NPIX / 256, 256, 0, stream>>>(x, lbl, W1, b1, W2, b2, W3, b3, W4, b4,
                                            W5, b5, out);
  }
}

// Round 20
// 157.021 us; speedup vs baseline: 1.0613x; 1.0613x over previous
//
#include <hip/hip_runtime.h>

// get_fc_pix_discriminator_1x1_solo: fused 5-layer per-pixel MLP + BCE mean.
// B=4, C=19, H=256, W=512 -> 524288 px. dims 19->64->128->256->512->1.
// R20 = exact revert to R18 (best measured: 180us/dispatch, 156us wall).
// R19's MX-scaled L4 regressed (191us): Bop hoist + A-assembly overflowed the
// 48-reg arch allocation at waves_per_eu(5,5) -> 34MB spill, and the scaled
// path's issue-slot count (4 b128 reads + 16 movs + 4 double-cycle MFMA per
// ob) matches the plain path (8 b64 reads + 16 MFMA) -- no net win.
// R18 state: VALUBusy 54% + MfmaUtil 44.5% ~= 98.5% combined -> SIMD issue
// stream saturated; all scheduling levers measured null. This is the
// structural ceiling of the design.

#define HW_ 131072      // 256*512 = 2^17
#define NPIX 524288

using bf16x8 = __attribute__((ext_vector_type(8))) short;
using f32x4  = __attribute__((ext_vector_type(4))) float;
using f32x2  = __attribute__((ext_vector_type(2))) float;
using fp8x8  = long;    // 8 fp8 bytes in one 64b register pair

#define MFMA  __builtin_amdgcn_mfma_f32_16x16x32_bf16
#define MFMA8 __builtin_amdgcn_mfma_f32_16x16x32_fp8_fp8
#define VMCNT2 asm volatile("s_waitcnt vmcnt(2)" ::: "memory")
#define VMCNT0 asm volatile("s_waitcnt vmcnt(0)" ::: "memory")
#define BAR __builtin_amdgcn_s_barrier()
#define SCHED0 __builtin_amdgcn_sched_barrier(0)

__device__ __forceinline__ unsigned short f2bf(float f) {
  unsigned u = __builtin_bit_cast(unsigned, f);
  u += 0x7FFFu + ((u >> 16) & 1u);   // round-to-nearest-even
  return (unsigned short)(u >> 16);
}

// sigma^-1: k-slot -> source feature index (within 32-chunks)
__device__ __forceinline__ int kinv(int k) {
  return ((k >> 5) << 5) + (((k >> 2) & 1) << 4) + (((k >> 3) & 3) << 2) + (k & 3);
}

// f32 -> fp8 e4m3 byte (RNE, saturating) via the HW packed converter
__device__ __forceinline__ unsigned char f2fp8(float f) {
  int v = __builtin_amdgcn_cvt_pk_fp8_f32(f, 0.f, 0, false);
  return (unsigned char)(v & 0xFF);
}

// ---- weight fp8 pre-conversion into MFMA A-fragment order -----------------
// frag space: [ob][ks][lane][j 0..8); o = ob*16+(lane&15),
// k = ks*32+(lane>>4)*8+j, feature f = PERM ? kinv(k) : k (0 if f>=K0).
// byte offset = ((ob*KS+ks)<<9) + lane*8 + j; one frag = 512B.
#define OW1 0
#define OW2 2048
#define OW3 10240
#define OW4 43008
#define WTOT 174080

template <int K0, int KP, bool PERM>
__device__ __forceinline__ void conv_layer(const float* __restrict__ W,
                                           unsigned char* __restrict__ out,
                                           int i) {
  int r9 = i & 511;
  int lane = r9 >> 3, j = r9 & 7;
  int frag = i >> 9;               // = ob*KS + ks
  constexpr int KS = KP / 32;
  int ob = frag / KS, ks = frag - ob * KS;
  int o = ob * 16 + (lane & 15);
  int k = ks * 32 + ((lane >> 4) << 3) + j;
  int f = PERM ? kinv(k) : k;
  out[i] = f2fp8(f < K0 ? W[o * K0 + f] : 0.f);
}

__global__ void wconv_kernel(const float* __restrict__ W1, const float* __restrict__ W2,
                             const float* __restrict__ W3, const float* __restrict__ W4,
                             unsigned char* __restrict__ wb) {
  int i = blockIdx.x * 256 + threadIdx.x;
  if (i < OW2) {
    conv_layer<19, 32, false>(W1, wb + OW1, i - OW1);
  } else if (i < OW3) {
    conv_layer<64, 64, true>(W2, wb + OW2, i - OW2);
  } else if (i < OW4) {
    conv_layer<128, 128, true>(W3, wb + OW3, i - OW3);
  } else if (i < WTOT) {
    conv_layer<256, 256, true>(W4, wb + OW4, i - OW4);
  }
}

// ---- packed-f32 helpers (VOP3P) -------------------------------------------
__device__ __forceinline__ f32x2 pk_mul(f32x2 a, f32x2 b) {
  f32x2 d;
  asm("v_pk_mul_f32 %0, %1, %2" : "=v"(d) : "v"(a), "v"(b));
  return d;
}
__device__ __forceinline__ f32x2 pk_fma(f32x2 a, f32x2 b, f32x2 c) {
  f32x2 d;
  asm("v_pk_fma_f32 %0, %1, %2, %3" : "=v"(d) : "v"(a), "v"(b), "v"(c));
  return d;
}

__device__ __forceinline__ f32x4 leaky4(f32x4 v) {
  f32x2 c = {0.2f, 0.2f};
  f32x2 lo = {v[0], v[1]}, hi = {v[2], v[3]};
  f32x2 ml = pk_mul(lo, c), mh = pk_mul(hi, c);
  f32x4 r;
  r[0] = fmaxf(v[0], ml[0]);
  r[1] = fmaxf(v[1], ml[1]);
  r[2] = fmaxf(v[2], mh[0]);
  r[3] = fmaxf(v[3], mh[1]);
  return r;
}

// pack 8 f32 -> 8 fp8 bytes (j order: e[0..3] -> bytes 0-3, o[0..3] -> 4-7)
__device__ __forceinline__ fp8x8 pack8f8(f32x4 e, f32x4 o) {
  int lo = __builtin_amdgcn_cvt_pk_fp8_f32(e[0], e[1], 0, false);
  lo = __builtin_amdgcn_cvt_pk_fp8_f32(e[2], e[3], lo, true);
  int hi = __builtin_amdgcn_cvt_pk_fp8_f32(o[0], o[1], 0, false);
  hi = __builtin_amdgcn_cvt_pk_fp8_f32(o[2], o[3], hi, true);
  return (long)(((unsigned long)(unsigned)hi << 32) | (unsigned)lo);
}

// ---- async global -> LDS staging (16B/lane, identity layout) --------------
__device__ __forceinline__ void gl16(const unsigned char* g, unsigned char* l) {
  __builtin_amdgcn_global_load_lds(
      (const __attribute__((address_space(1))) unsigned int*)(const void*)g,
      (__attribute__((address_space(3))) unsigned int*)(void*)l, 16, 0, 0);
}
// one 8KB chunk = 8 x 1KB segments; 4 waves round-robin (2 segs/wave)
__device__ __forceinline__ void stage8(const unsigned char* __restrict__ g,
                                       unsigned char* l, int wave, int lane) {
#pragma unroll
  for (int i = 0; i < 2; i++) {
    int s = wave + 4 * i;
    gl16(g + (s << 10) + (lane << 4), l + (s << 10));
  }
}

// frag read from LDS chunk: local frag lf (512B each), lane-linear 8B
#define LDF8(bufp, lf) (*(const fp8x8*)((bufp) + ((lf) << 9) + (lane << 3)))

__global__ __launch_bounds__(256) __attribute__((amdgpu_waves_per_eu(5, 5)))
void disc_lds(const float* __restrict__ x, const float* __restrict__ lbl,
              const unsigned char* __restrict__ wb8,
              const float* __restrict__ b1, const float* __restrict__ b2,
              const float* __restrict__ b3, const float* __restrict__ b4,
              const float* __restrict__ W5f, const float* __restrict__ b5,
              float* __restrict__ out) {
  __shared__ __align__(16) unsigned char sb[24576];  // 3 x 8KB tri-buffer
  // total LDS = 24576 B -> 5 WGs/CU at waves_per_eu(5,5) (120KB <= 160KB).

  int t = threadIdx.x;
  int wave = t >> 6, lane = t & 63;
  int g = lane >> 4, li = lane & 15;
  long px0 = ((long)blockIdx.x * 4 + wave) * 32;   // 32 px per wave
  int b = (int)(px0 >> 17);
  int hw0 = (int)(px0 & (HW_ - 1));

  // ---- W1 frags direct global->reg (2KB, L2-resident broadcast) ----------
  fp8x8 fW1[4];
#pragma unroll
  for (int f = 0; f < 4; f++)
    fW1[f] = *(const fp8x8*)(wb8 + (f << 9) + (lane << 3));

  // ---- x -> fp8 B-frags (k = input channel c; c>=19 zero) -----------------
  fp8x8 xb[2];
#pragma unroll
  for (int pb = 0; pb < 2; pb++) {
    const float* xp = x + (((long)b * 19) << 17) + hw0 + pb * 16 + li;
    f32x4 e, o;
#pragma unroll
    for (int j = 0; j < 4; j++) {
      int c = 8 * g + j;
      e[j] = (c < 19) ? xp[(long)c << 17] : 0.f;
      int c2 = 8 * g + 4 + j;
      o[j] = (c2 < 19) ? xp[(long)c2 << 17] : 0.f;
    }
    xb[pb] = pack8f8(e, o);
  }

  // ---- issue pipeline chunks 0 (W2 -> buf0) and 1 (W3a -> buf1) -----------
  stage8(wb8 + OW2, sb, wave, lane);
  stage8(wb8 + OW3, sb + 8192, wave, lane);

  // ---- L1: 19->64 from fW1 regs -------------------------------------------
  fp8x8 h1[2][2];
#pragma unroll
  for (int obp = 0; obp < 2; obp++) {
    f32x4 bE = *(const f32x4*)(b1 + 32 * obp + 4 * g);
    f32x4 bO = *(const f32x4*)(b1 + 32 * obp + 16 + 4 * g);
    f32x4 aE[2], aO[2];
#pragma unroll
    for (int pb = 0; pb < 2; pb++) {
      aE[pb] = MFMA8(fW1[2 * obp], xb[pb], bE, 0, 0, 0);
      aO[pb] = MFMA8(fW1[2 * obp + 1], xb[pb], bO, 0, 0, 0);
    }
#pragma unroll
    for (int pb = 0; pb < 2; pb++)
      h1[pb][obp] = pack8f8(leaky4(aE[pb]), leaky4(aO[pb]));
  }

  // ---- phase 0: L2 from buf0 (chunk 0 = W2); stage chunk 2 -> buf2 --------
  VMCNT2; BAR; SCHED0;
  stage8(wb8 + OW3 + 8192, sb + 16384, wave, lane);
  fp8x8 h2[2][4];
  {
    const unsigned char* cur = sb;
#pragma unroll
    for (int obp = 0; obp < 4; obp++) {
      fp8x8 fE0 = LDF8(cur, 4 * obp);
      fp8x8 fE1 = LDF8(cur, 4 * obp + 1);
      fp8x8 fO0 = LDF8(cur, 4 * obp + 2);
      fp8x8 fO1 = LDF8(cur, 4 * obp + 3);
      f32x4 bE = *(const f32x4*)(b2 + 32 * obp + 4 * g);
      f32x4 bO = *(const f32x4*)(b2 + 32 * obp + 16 + 4 * g);
      f32x4 aE[2], aO[2];
#pragma unroll
      for (int pb = 0; pb < 2; pb++) {
        aE[pb] = MFMA8(fE0, h1[pb][0], bE, 0, 0, 0);
        aE[pb] = MFMA8(fE1, h1[pb][1], aE[pb], 0, 0, 0);
        aO[pb] = MFMA8(fO0, h1[pb][0], bO, 0, 0, 0);
        aO[pb] = MFMA8(fO1, h1[pb][1], aO[pb], 0, 0, 0);
      }
#pragma unroll
      for (int pb = 0; pb < 2; pb++)
        h2[pb][obp] = pack8f8(leaky4(aE[pb]), leaky4(aO[pb]));
    }
  }

  // ---- phases 1-4: L3 (chunk c=1+k covers obp {2k, 2k+1}) -----------------
  fp8x8 h3[2][8];
#pragma unroll
  for (int k = 0; k < 4; k++) {
    int c = 1 + k;
    VMCNT2; BAR; SCHED0;
    // stage chunk c+2: chunks 3,4 = W3 tail; 5,6 = W4 head
    int cc = c + 2;
    const unsigned char* src = (cc <= 4) ? (wb8 + OW3 + ((cc - 1) << 13))
                                         : (wb8 + OW4 + ((cc - 5) << 13));
    stage8(src, sb + ((cc % 3) << 13), wave, lane);
    const unsigned char* cur = sb + ((c % 3) << 13);
#pragma unroll
    for (int o = 0; o < 2; o++) {
      int obp = 2 * k + o;
      f32x4 bE = *(const f32x4*)(b3 + 32 * obp + 4 * g);
      f32x4 bO = *(const f32x4*)(b3 + 32 * obp + 16 + 4 * g);
      f32x4 aE[2], aO[2];
#pragma unroll
      for (int pb = 0; pb < 2; pb++) { aE[pb] = bE; aO[pb] = bO; }
#pragma unroll
      for (int ks = 0; ks < 4; ks++) {
        fp8x8 fE = LDF8(cur, o * 8 + ks);
        fp8x8 fO = LDF8(cur, o * 8 + 4 + ks);
#pragma unroll
        for (int pb = 0; pb < 2; pb++) {
          aE[pb] = MFMA8(fE, h2[pb][ks], aE[pb], 0, 0, 0);
          aO[pb] = MFMA8(fO, h2[pb][ks], aO[pb], 0, 0, 0);
        }
      }
#pragma unroll
      for (int pb = 0; pb < 2; pb++)
        h3[pb][obp] = pack8f8(leaky4(aE[pb]), leaky4(aO[pb]));
    }
  }

  // ---- phases 5-20: L4+L5 (chunk c covers obs {2(c-5), 2(c-5)+1}) ---------
  f32x2 zplo[2], zphi[2];
#pragma unroll
  for (int pb = 0; pb < 2; pb++) {
    zplo[pb] = f32x2{0.f, 0.f};
    zphi[pb] = f32x2{0.f, 0.f};
  }

#pragma unroll 1
  for (int c = 5; c <= 20; c++) {
    if (c == 20) { VMCNT0; } else { VMCNT2; }
    BAR; SCHED0;
    if (c + 2 <= 20)
      stage8(wb8 + OW4 + ((c - 3) << 13), sb + (((c + 2) % 3) << 13),
             wave, lane);
    const unsigned char* cur = sb + ((c % 3) << 13);
    int ob0 = 2 * (c - 5);
#pragma unroll
    for (int oo = 0; oo < 2; oo++) {
      int ob = ob0 + oo;
      f32x4 bv = *(const f32x4*)(b4 + 16 * ob + 4 * g);
      f32x4 w5v = *(const f32x4*)(W5f + 16 * ob + 4 * g);
      f32x4 a[2];
#pragma unroll
      for (int pb = 0; pb < 2; pb++) a[pb] = bv;
#pragma unroll
      for (int ks = 0; ks < 8; ks++) {
        fp8x8 f4 = LDF8(cur, oo * 8 + ks);
#pragma unroll
        for (int pb = 0; pb < 2; pb++) a[pb] = MFMA8(f4, h3[pb][ks], a[pb], 0, 0, 0);
      }
#pragma unroll
      for (int pb = 0; pb < 2; pb++) {
        f32x4 lv = leaky4(a[pb]);
        zplo[pb] = pk_fma(f32x2{lv[0], lv[1]}, f32x2{w5v[0], w5v[1]}, zplo[pb]);
        zphi[pb] = pk_fma(f32x2{lv[2], lv[3]}, f32x2{w5v[2], w5v[3]}, zphi[pb]);
      }
    }
  }

  // ---- z per pixel + BCE + reduction (reuse sb bytes for 4 floats) --------
  float zb[2];
#pragma unroll
  for (int pb = 0; pb < 2; pb++) {
    float s = zplo[pb][0] + zplo[pb][1] + zphi[pb][0] + zphi[pb][1];
    s += __shfl_xor(s, 16);
    s += __shfl_xor(s, 32);
    zb[pb] = s;  // full z for px (pb,li), replicated across g
  }
  // lanes 0-15 -> pb0 px, lanes 16-31 -> pb1 px, lanes 32-63 idle
  float w = 0.f;
  if (lane < 32) {
    float z = ((lane & 16) ? zb[1] : zb[0]) + b5[0];
    float lab = lbl[px0 + lane];
    w = fmaxf(z, 0.f) - z * lab + log1pf(expf(-fabsf(z)));
  }
#pragma unroll
  for (int m = 1; m <= 32; m <<= 1) w += __shfl_xor(w, m);
  float* zsp = (float*)sb;   // chunk-20 region is sb+16384; sb+0 is free
  if (lane == 0) zsp[wave] = w;
  __syncthreads();
  if (t == 0)
    atomicAdd(out, (zsp[0] + zsp[1] + zsp[2] + zsp[3]) * (1.f / (float)NPIX));
}

// ---- fallback (ws too small): bf16 register-chained kernel, direct gather -
__device__ __forceinline__ f32x4 leaky4s(f32x4 v) {
  f32x4 r;
#pragma unroll
  for (int i = 0; i < 4; i++) r[i] = fmaxf(v[i], 0.2f * v[i]);
  return r;
}
__device__ __forceinline__ unsigned cvtpk(float lo, float hi) {
  unsigned r;
  asm("v_cvt_pk_bf16_f32 %0, %1, %2" : "=v"(r) : "v"(lo), "v"(hi));
  return r;
}
__device__ __forceinline__ bf16x8 pack8(f32x4 e, f32x4 o) {
  union { unsigned u[4]; bf16x8 v; } r;
  r.u[0] = cvtpk(e[0], e[1]);
  r.u[1] = cvtpk(e[2], e[3]);
  r.u[2] = cvtpk(o[0], o[1]);
  r.u[3] = cvtpk(o[2], o[3]);
  return r.v;
}
#define LDAG(dst, Wf, K0, KP, PERM, ob, ks)                                    \
  do {                                                                         \
    int o_ = (ob) * 16 + li;                                                   \
    for (int j_ = 0; j_ < 8; j_++) {                                           \
      int k_ = (ks) * 32 + (g << 3) + j_;                                      \
      int f_ = (PERM) ? kinv(k_) : k_;                                         \
      float v_ = f_ < (K0) ? (Wf)[o_ * (K0) + f_] : 0.f;                       \
      dst[j_] = (short)f2bf(v_);                                               \
    }                                                                          \
  } while (0)

__global__ __launch_bounds__(256, 1) void disc_fb(
    const float* __restrict__ x, const float* __restrict__ lbl,
    const float* __restrict__ W1f, const float* __restrict__ b1,
    const float* __restrict__ W2f, const float* __restrict__ b2,
    const float* __restrict__ W3f, const float* __restrict__ b3,
    const float* __restrict__ W4f, const float* __restrict__ b4,
    const float* __restrict__ W5f, const float* __restrict__ b5,
    float* __restrict__ out) {
  __shared__ float zs[4];
  int t = threadIdx.x;
  int wave = t >> 6, lane = t & 63;
  int g = lane >> 4, li = lane & 15;
  long px0 = ((long)blockIdx.x * 4 + wave) * 64;
  int b = (int)(px0 >> 17);
  int hw0 = (int)(px0 & (HW_ - 1));

  bf16x8 xb[4];
#pragma unroll
  for (int pb = 0; pb < 4; pb++) {
    const float* xp = x + (((long)b * 19) << 17) + hw0 + pb * 16 + li;
    bf16x8 v;
#pragma unroll
    for (int j = 0; j < 8; j++) {
      int c = 8 * g + j;
      float f = (c < 19) ? xp[(long)c << 17] : 0.f;
      v[j] = (short)f2bf(f);
    }
    xb[pb] = v;
  }

  bf16x8 h1[4][2];
#pragma unroll
  for (int obp = 0; obp < 2; obp++) {
    bf16x8 fE, fO;
    LDAG(fE, W1f, 19, 32, false, 2 * obp, 0);
    LDAG(fO, W1f, 19, 32, false, 2 * obp + 1, 0);
    f32x4 bE = *(const f32x4*)(b1 + 32 * obp + 4 * g);
    f32x4 bO = *(const f32x4*)(b1 + 32 * obp + 16 + 4 * g);
#pragma unroll
    for (int pb = 0; pb < 4; pb++) {
      f32x4 aE = MFMA(fE, xb[pb], bE, 0, 0, 0);
      f32x4 aO = MFMA(fO, xb[pb], bO, 0, 0, 0);
      h1[pb][obp] = pack8(leaky4s(aE), leaky4s(aO));
    }
  }

  bf16x8 h2[4][4];
#pragma unroll
  for (int obp = 0; obp < 4; obp++) {
    bf16x8 fE0, fE1, fO0, fO1;
    LDAG(fE0, W2f, 64, 64, true, 2 * obp, 0);
    LDAG(fE1, W2f, 64, 64, true, 2 * obp, 1);
    LDAG(fO0, W2f, 64, 64, true, 2 * obp + 1, 0);
    LDAG(fO1, W2f, 64, 64, true, 2 * obp + 1, 1);
    f32x4 bE = *(const f32x4*)(b2 + 32 * obp + 4 * g);
    f32x4 bO = *(const f32x4*)(b2 + 32 * obp + 16 + 4 * g);
#pragma unroll
    for (int pb = 0; pb < 4; pb++) {
      f32x4 aE = MFMA(fE0, h1[pb][0], bE, 0, 0, 0);
      aE = MFMA(fE1, h1[pb][1], aE, 0, 0, 0);
      f32x4 aO = MFMA(fO0, h1[pb][0], bO, 0, 0, 0);
      aO = MFMA(fO1, h1[pb][1], aO, 0, 0, 0);
      h2[pb][obp] = pack8(leaky4s(aE), leaky4s(aO));
    }
  }

  bf16x8 h3[4][8];
#pragma unroll
  for (int obp = 0; obp < 8; obp++) {
    f32x4 bE = *(const f32x4*)(b3 + 32 * obp + 4 * g);
    f32x4 bO = *(const f32x4*)(b3 + 32 * obp + 16 + 4 * g);
    f32x4 aE[4], aO[4];
#pragma unroll
    for (int pb = 0; pb < 4; pb++) { aE[pb] = bE; aO[pb] = bO; }
#pragma unroll
    for (int ks = 0; ks < 4; ks++) {
      bf16x8 fE, fO;
      LDAG(fE, W3f, 128, 128, true, 2 * obp, ks);
      LDAG(fO, W3f, 128, 128, true, 2 * obp + 1, ks);
#pragma unroll
      for (int pb = 0; pb < 4; pb++) {
        aE[pb] = MFMA(fE, h2[pb][ks], aE[pb], 0, 0, 0);
        aO[pb] = MFMA(fO, h2[pb][ks], aO[pb], 0, 0, 0);
      }
    }
#pragma unroll
    for (int pb = 0; pb < 4; pb++)
      h3[pb][obp] = pack8(leaky4s(aE[pb]), leaky4s(aO[pb]));
  }

  f32x4 zp[4];
#pragma unroll
  for (int pb = 0; pb < 4; pb++) zp[pb] = f32x4{0.f, 0.f, 0.f, 0.f};

  for (int ob = 0; ob < 32; ob++) {
    f32x4 bv = *(const f32x4*)(b4 + 16 * ob + 4 * g);
    f32x4 w5v = *(const f32x4*)(W5f + 16 * ob + 4 * g);
    f32x4 a[4];
#pragma unroll
    for (int pb = 0; pb < 4; pb++) a[pb] = bv;
#pragma unroll
    for (int ks = 0; ks < 8; ks++) {
      bf16x8 f4;
      LDAG(f4, W4f, 256, 256, true, ob, ks);
#pragma unroll
      for (int pb = 0; pb < 4; pb++) a[pb] = MFMA(f4, h3[pb][ks], a[pb], 0, 0, 0);
    }
#pragma unroll
    for (int pb = 0; pb < 4; pb++) {
      f32x4 lv = leaky4s(a[pb]);
#pragma unroll
      for (int i = 0; i < 4; i++) zp[pb][i] = fmaf(lv[i], w5v[i], zp[pb][i]);
    }
  }

  float zb[4];
#pragma unroll
  for (int pb = 0; pb < 4; pb++) {
    float s = zp[pb][0] + zp[pb][1] + zp[pb][2] + zp[pb][3];
    s += __shfl_xor(s, 16);
    s += __shfl_xor(s, 32);
    zb[pb] = s;
  }
  float zsel = (g == 0) ? zb[0] : (g == 1) ? zb[1] : (g == 2) ? zb[2] : zb[3];
  float z = zsel + b5[0];
  float lab = lbl[px0 + lane];
  float w = fmaxf(z, 0.f) - z * lab + log1pf(expf(-fabsf(z)));
#pragma unroll
  for (int m = 1; m <= 32; m <<= 1) w += __shfl_xor(w, m);
  if (lane == 0) zs[wave] = w;
  __syncthreads();
  if (t == 0)
    atomicAdd(out, (zs[0] + zs[1] + zs[2] + zs[3]) * (1.f / (float)NPIX));
}

extern "C" void kernel_launch(void* const* d_in, const int* in_sizes, int n_in,
                              void* d_out, int out_size, void* d_ws, size_t ws_size,
                              hipStream_t stream) {
  const float* x   = (const float*)d_in[0];
  const float* lbl = (const float*)d_in[1];
  const float* W1  = (const float*)d_in[2];
  const float* b1  = (const float*)d_in[3];
  const float* W2  = (const float*)d_in[4];
  const float* b2  = (const float*)d_in[5];
  const float* W3  = (const float*)d_in[6];
  const float* b3  = (const float*)d_in[7];
  const float* W4  = (const float*)d_in[8];
  const float* b4  = (const float*)d_in[9];
  const float* W5  = (const float*)d_in[10];
  const float* b5  = (const float*)d_in[11];
  float* out = (float*)d_out;

  (void)hipMemsetAsync(d_out, 0, sizeof(float), stream);

  bool pre = ws_size >= (size_t)WTOT;
  if (pre) {
    unsigned char* wbp = (unsigned char*)d_ws;
    wconv_kernel<<<(WTOT + 255) / 256, 256, 0, stream>>>(W1, W2, W3, W4, wbp);
    disc_lds<<<NPIX / 128, 256, 0, stream>>>(x, lbl, wbp, b1, b2, b3, b4, W5, b5, out);
  } else {
    disc_fb<<<NPIX / 256, 256, 0, stream>>>(x, lbl, W1, b1, W2, b2, W3, b3, W4, b4,
                                            W5, b5, out);
  }
}